// Round 1
// baseline (406.884 us; speedup 1.0000x reference)
//
#include <hip/hip_runtime.h>
#include <hip/hip_bf16.h>

// GroupFC: C[32768,1024] = A[32768,1024] @ W[1024,1024]^T + b[1024], fp32 in/out.
// bf16 MFMA GEMM (tolerance permits bf16 inputs), fp32 accumulate.
// 128x128 tile, BK=32, 256 threads (4 waves, each 64x64 as 4x4 of 16x16x32 MFMA).

#define M_DIM 32768
#define N_DIM 1024
#define K_DIM 1024
#define BM 128
#define BN 128
#define BK 32
#define LDK 40  // padded LDS K-stride (elements); 80B row stride -> <=2-way bank conflict (free)

typedef __attribute__((ext_vector_type(8))) short bf16x8;
typedef __attribute__((ext_vector_type(4))) float f32x4;

static __device__ __forceinline__ unsigned short f2bf(float x) {
    __hip_bfloat16 h = __float2bfloat16(x);  // RNE
    union { __hip_bfloat16 h; unsigned short u; } cv;
    cv.h = h;
    return cv.u;
}

__global__ __launch_bounds__(256) void groupfc_gemm(
    const float* __restrict__ A,     // [M,K]
    const float* __restrict__ W,     // [N,K]
    const float* __restrict__ bias,  // [N]
    float* __restrict__ C)           // [M,N]
{
    __shared__ unsigned short As[BM * LDK];
    __shared__ unsigned short Bs[BN * LDK];

    const int tid  = threadIdx.x;
    const int bm0  = blockIdx.x * BM;
    const int bn0  = blockIdx.y * BN;

    const int wave = tid >> 6;
    const int lane = tid & 63;
    const int wr   = wave >> 1;   // wave row 0..1 (64-row slab)
    const int wc   = wave & 1;    // wave col 0..1 (64-col slab)
    const int l15  = lane & 15;
    const int quad = lane >> 4;   // 0..3

    f32x4 acc[4][4];
#pragma unroll
    for (int i = 0; i < 4; ++i)
#pragma unroll
        for (int j = 0; j < 4; ++j)
            acc[i][j] = (f32x4){0.f, 0.f, 0.f, 0.f};

    // staging mapping: per pass, 32 rows x 8 float4 (=32 floats) per row
    const int srow = tid >> 3;  // 0..31
    const int sf4  = tid & 7;   // 0..7

    const float* Ag = A + bm0 * K_DIM;
    const float* Wg = W + bn0 * K_DIM;

    for (int kt = 0; kt < K_DIM; kt += BK) {
        __syncthreads();

        // ---- global -> regs (fp32) ----
        float4 av[4], bv[4];
#pragma unroll
        for (int p = 0; p < 4; ++p) {
            const int row = p * 32 + srow;
            av[p] = *(const float4*)(Ag + row * K_DIM + kt + sf4 * 4);
            bv[p] = *(const float4*)(Wg + row * K_DIM + kt + sf4 * 4);
        }

        // ---- convert fp32 -> bf16, write LDS ----
#pragma unroll
        for (int p = 0; p < 4; ++p) {
            const int row = p * 32 + srow;
            ushort4 a16, b16;
            a16.x = f2bf(av[p].x); a16.y = f2bf(av[p].y);
            a16.z = f2bf(av[p].z); a16.w = f2bf(av[p].w);
            b16.x = f2bf(bv[p].x); b16.y = f2bf(bv[p].y);
            b16.z = f2bf(bv[p].z); b16.w = f2bf(bv[p].w);
            *(ushort4*)(&As[row * LDK + sf4 * 4]) = a16;  // 8B ds_write_b64
            *(ushort4*)(&Bs[row * LDK + sf4 * 4]) = b16;
        }

        __syncthreads();

        // ---- LDS -> frags, MFMA ----
        bf16x8 afrag[4], bfrag[4];
#pragma unroll
        for (int i = 0; i < 4; ++i) {
            const int arow = wr * 64 + i * 16 + l15;
            afrag[i] = *(const bf16x8*)(&As[arow * LDK + quad * 8]);  // 16B ds_read_b128
            const int brow = wc * 64 + i * 16 + l15;
            bfrag[i] = *(const bf16x8*)(&Bs[brow * LDK + quad * 8]);
        }
#pragma unroll
        for (int i = 0; i < 4; ++i)
#pragma unroll
            for (int j = 0; j < 4; ++j)
                acc[i][j] = __builtin_amdgcn_mfma_f32_16x16x32_bf16(
                    afrag[i], bfrag[j], acc[i][j], 0, 0, 0);
    }

    // ---- epilogue: + bias, store fp32 ----
    // C/D layout (16x16): col = lane&15, row = quad*4 + reg   [m89/m91 verified]
#pragma unroll
    for (int j = 0; j < 4; ++j) {
        const int col = bn0 + wc * 64 + j * 16 + l15;
        const float bj = bias[col];
#pragma unroll
        for (int i = 0; i < 4; ++i) {
            const int row0 = bm0 + wr * 64 + i * 16 + quad * 4;
#pragma unroll
            for (int r = 0; r < 4; ++r) {
                C[(row0 + r) * N_DIM + col] = acc[i][j][r] + bj;
            }
        }
    }
}

extern "C" void kernel_launch(void* const* d_in, const int* in_sizes, int n_in,
                              void* d_out, int out_size, void* d_ws, size_t ws_size,
                              hipStream_t stream) {
    const float* A    = (const float*)d_in[0];  // data  [32768,1024]
    const float* W    = (const float*)d_in[1];  // W     [1024,1024]
    const float* bias = (const float*)d_in[2];  // b     [1024]
    float* C          = (float*)d_out;          // out   [32768,1024]

    dim3 grid(M_DIM / BM, N_DIM / BN);  // (256, 8)
    dim3 block(256);
    groupfc_gemm<<<grid, block, 0, stream>>>(A, W, bias, C);
}

// Round 2
// 326.136 us; speedup vs baseline: 1.2476x; 1.2476x over previous
//
#include <hip/hip_runtime.h>
#include <hip/hip_bf16.h>

// GroupFC: C[32768,1024] = A[32768,1024] @ W[1024,1024]^T + b[1024], fp32 in/out.
// R2: two-pass. (1) convert A,W -> bf16 in d_ws once. (2) m97-style MFMA GEMM:
// global_load_lds width=16 staging with XOR chunk swizzle (conflict-free,
// zero staging VALU), 128x128 tile, BK=64, 16x16x32 bf16 MFMA, fp32 out + bias.

#define M_DIM 32768
#define N_DIM 1024
#define K_DIM 1024
#define BM 128
#define BN 128
#define BK 64

typedef __attribute__((ext_vector_type(8))) short bf16x8;
typedef __attribute__((ext_vector_type(4))) float f32x4;
typedef __attribute__((ext_vector_type(8))) unsigned short ushort8v;

typedef const __attribute__((address_space(1))) unsigned int* gptr_t;
typedef __attribute__((address_space(3))) unsigned int* lptr_t;

static __device__ __forceinline__ unsigned short f2bf(float x) {
    union { __hip_bfloat16 h; unsigned short u; } cv;
    cv.h = __float2bfloat16(x);  // RNE
    return cv.u;
}

// ---------------- pass 1: fp32 -> bf16 convert ----------------
__global__ __launch_bounds__(256) void convert_f32_bf16(
    const float* __restrict__ in, unsigned short* __restrict__ out) {
    const int idx = (blockIdx.x * 256 + threadIdx.x) * 8;
    float4 v0 = *(const float4*)(in + idx);
    float4 v1 = *(const float4*)(in + idx + 4);
    ushort8v o;
    o[0] = f2bf(v0.x); o[1] = f2bf(v0.y); o[2] = f2bf(v0.z); o[3] = f2bf(v0.w);
    o[4] = f2bf(v1.x); o[5] = f2bf(v1.y); o[6] = f2bf(v1.z); o[7] = f2bf(v1.w);
    *(ushort8v*)(out + idx) = o;  // 16B store
}

// ---------------- pass 2: bf16 MFMA GEMM ----------------
// LDS layout: tile stored as 128 rows x 8 chunks (chunk = 8 bf16 = 16B),
// chunk c of row r lives at slot r*8 + (c ^ (r&7)).  global_load_lds fills
// slots in lane order (base + lane*16); each lane fetches the global chunk
// that belongs in its slot.
__global__ __launch_bounds__(256) void gemm_bf16(
    const unsigned short* __restrict__ A,   // [M,K] bf16
    const unsigned short* __restrict__ W,   // [N,K] bf16
    const float* __restrict__ bias,         // [N]
    float* __restrict__ C)                  // [M,N] fp32
{
    __shared__ unsigned short As[BM * BK];  // 16 KB
    __shared__ unsigned short Bs[BN * BK];  // 16 KB

    const int tid  = threadIdx.x;
    const int wave = tid >> 6;
    const int lane = tid & 63;
    const int bm0  = blockIdx.x * BM;
    const int bn0  = blockIdx.y * BN;
    const int wr   = wave >> 1;
    const int wc   = wave & 1;
    const int l15  = lane & 15;
    const int quad = lane >> 4;

    f32x4 acc[4][4];
#pragma unroll
    for (int i = 0; i < 4; ++i)
#pragma unroll
        for (int j = 0; j < 4; ++j)
            acc[i][j] = (f32x4){0.f, 0.f, 0.f, 0.f};

    const unsigned short* Ag = A + bm0 * K_DIM;
    const unsigned short* Wg = W + bn0 * K_DIM;

    // per-pass slot for this lane: s = p*256 + wave*64 + lane
    // row = s>>3 (8 lanes per 64-elem row), cpos = s&7, global chunk = cpos^(row&7)
    for (int kt = 0; kt < K_DIM; kt += BK) {
        __syncthreads();
#pragma unroll
        for (int p = 0; p < 4; ++p) {
            const int s    = p * 256 + wave * 64 + lane;
            const int row  = s >> 3;
            const int c    = (s & 7) ^ (row & 7);
            const int goff = row * K_DIM + kt + c * 8;      // elems
            const int lbase = (p * 256 + wave * 64) * 8;    // elems (wave-uniform)
            __builtin_amdgcn_global_load_lds((gptr_t)(Ag + goff), (lptr_t)(As + lbase), 16, 0, 0);
            __builtin_amdgcn_global_load_lds((gptr_t)(Wg + goff), (lptr_t)(Bs + lbase), 16, 0, 0);
        }
        __syncthreads();

#pragma unroll
        for (int kk = 0; kk < 2; ++kk) {
            bf16x8 af[4], bf[4];
#pragma unroll
            for (int i = 0; i < 4; ++i) {
                const int arow = wr * 64 + i * 16 + l15;
                const int ac   = (kk * 4 + quad) ^ (arow & 7);
                af[i] = *(const bf16x8*)(As + arow * 64 + ac * 8);   // ds_read_b128
                const int brow = wc * 64 + i * 16 + l15;
                const int bc   = (kk * 4 + quad) ^ (brow & 7);
                bf[i] = *(const bf16x8*)(Bs + brow * 64 + bc * 8);
            }
#pragma unroll
            for (int i = 0; i < 4; ++i)
#pragma unroll
                for (int j = 0; j < 4; ++j)
                    acc[i][j] = __builtin_amdgcn_mfma_f32_16x16x32_bf16(
                        af[i], bf[j], acc[i][j], 0, 0, 0);
        }
    }

    // epilogue: + bias, fp32 store.  C/D: col = lane&15, row = quad*4 + reg
#pragma unroll
    for (int j = 0; j < 4; ++j) {
        const int col = bn0 + wc * 64 + j * 16 + l15;
        const float bj = bias[col];
#pragma unroll
        for (int i = 0; i < 4; ++i) {
            const int row0 = bm0 + wr * 64 + i * 16 + quad * 4;
#pragma unroll
            for (int r = 0; r < 4; ++r) {
                C[(row0 + r) * N_DIM + col] = acc[i][j][r] + bj;
            }
        }
    }
}

// ---------------- fallback (R1 fused) if d_ws too small ----------------
#define LDK 40
__global__ __launch_bounds__(256) void groupfc_fused(
    const float* __restrict__ A, const float* __restrict__ W,
    const float* __restrict__ bias, float* __restrict__ C)
{
    __shared__ unsigned short As[BM * LDK];
    __shared__ unsigned short Bs[BN * LDK];
    const int tid = threadIdx.x;
    const int bm0 = blockIdx.x * BM, bn0 = blockIdx.y * BN;
    const int wave = tid >> 6, lane = tid & 63;
    const int wr = wave >> 1, wc = wave & 1;
    const int l15 = lane & 15, quad = lane >> 4;
    f32x4 acc[4][4];
#pragma unroll
    for (int i = 0; i < 4; ++i)
#pragma unroll
        for (int j = 0; j < 4; ++j) acc[i][j] = (f32x4){0.f, 0.f, 0.f, 0.f};
    const int srow = tid >> 3, sf4 = tid & 7;
    const float* Ag = A + bm0 * K_DIM;
    const float* Wg = W + bn0 * K_DIM;
    for (int kt = 0; kt < K_DIM; kt += 32) {
        __syncthreads();
        float4 av[4], bv[4];
#pragma unroll
        for (int p = 0; p < 4; ++p) {
            const int row = p * 32 + srow;
            av[p] = *(const float4*)(Ag + row * K_DIM + kt + sf4 * 4);
            bv[p] = *(const float4*)(Wg + row * K_DIM + kt + sf4 * 4);
        }
#pragma unroll
        for (int p = 0; p < 4; ++p) {
            const int row = p * 32 + srow;
            ushort4 a16, b16;
            a16.x = f2bf(av[p].x); a16.y = f2bf(av[p].y);
            a16.z = f2bf(av[p].z); a16.w = f2bf(av[p].w);
            b16.x = f2bf(bv[p].x); b16.y = f2bf(bv[p].y);
            b16.z = f2bf(bv[p].z); b16.w = f2bf(bv[p].w);
            *(ushort4*)(&As[row * LDK + sf4 * 4]) = a16;
            *(ushort4*)(&Bs[row * LDK + sf4 * 4]) = b16;
        }
        __syncthreads();
        bf16x8 af[4], bf[4];
#pragma unroll
        for (int i = 0; i < 4; ++i) {
            af[i] = *(const bf16x8*)(&As[(wr * 64 + i * 16 + l15) * LDK + quad * 8]);
            bf[i] = *(const bf16x8*)(&Bs[(wc * 64 + i * 16 + l15) * LDK + quad * 8]);
        }
#pragma unroll
        for (int i = 0; i < 4; ++i)
#pragma unroll
            for (int j = 0; j < 4; ++j)
                acc[i][j] = __builtin_amdgcn_mfma_f32_16x16x32_bf16(af[i], bf[j], acc[i][j], 0, 0, 0);
    }
#pragma unroll
    for (int j = 0; j < 4; ++j) {
        const int col = bn0 + wc * 64 + j * 16 + l15;
        const float bj = bias[col];
#pragma unroll
        for (int i = 0; i < 4; ++i) {
            const int row0 = bm0 + wr * 64 + i * 16 + quad * 4;
#pragma unroll
            for (int r = 0; r < 4; ++r) C[(row0 + r) * N_DIM + col] = acc[i][j][r] + bj;
        }
    }
}

extern "C" void kernel_launch(void* const* d_in, const int* in_sizes, int n_in,
                              void* d_out, int out_size, void* d_ws, size_t ws_size,
                              hipStream_t stream) {
    const float* A    = (const float*)d_in[0];
    const float* W    = (const float*)d_in[1];
    const float* bias = (const float*)d_in[2];
    float* C          = (float*)d_out;

    const size_t a_elems = (size_t)M_DIM * K_DIM;       // 33.5M
    const size_t w_elems = (size_t)N_DIM * K_DIM;       // 1.05M
    const size_t need    = (a_elems + w_elems) * sizeof(unsigned short);  // ~66 MB

    if (ws_size >= need) {
        unsigned short* Abf = (unsigned short*)d_ws;
        unsigned short* Wbf = Abf + a_elems;
        convert_f32_bf16<<<dim3(a_elems / (256 * 8)), dim3(256), 0, stream>>>(A, Abf);
        convert_f32_bf16<<<dim3(w_elems / (256 * 8)), dim3(256), 0, stream>>>(W, Wbf);
        dim3 grid(M_DIM / BM, N_DIM / BN);  // (256, 8)
        gemm_bf16<<<grid, dim3(256), 0, stream>>>(Abf, Wbf, bias, C);
    } else {
        dim3 grid(M_DIM / BM, N_DIM / BN);
        groupfc_fused<<<grid, dim3(256), 0, stream>>>(A, W, bias, C);
    }
}

// Round 3
// 315.704 us; speedup vs baseline: 1.2888x; 1.0330x over previous
//
#include <hip/hip_runtime.h>
#include <hip/hip_bf16.h>

// GroupFC: C[32768,1024] = A[32768,1024] @ W[1024,1024]^T + b[1024], fp32 in/out.
// R3: (1) convert A,W -> bf16 once in d_ws. (2) MFMA GEMM with 32x32x16 bf16
// (4096 FLOP/cyc/CU vs 3378 for 16x16x32), global_load_lds width=16 staging with
// XOR chunk swizzle, 128x128 tile, BK=64, grid swizzled so the 8 N-tiles of one
// M-tile are dispatch-adjacent (A-tile LLC reuse).

#define M_DIM 32768
#define N_DIM 1024
#define K_DIM 1024
#define BM 128
#define BN 128
#define BK 64

typedef __attribute__((ext_vector_type(8))) short bf16x8;
typedef __attribute__((ext_vector_type(4))) float f32x4;
typedef __attribute__((ext_vector_type(16))) float f32x16;
typedef __attribute__((ext_vector_type(8))) unsigned short ushort8v;

typedef const __attribute__((address_space(1))) unsigned int* gptr_t;
typedef __attribute__((address_space(3))) unsigned int* lptr_t;

static __device__ __forceinline__ unsigned short f2bf(float x) {
    union { __hip_bfloat16 h; unsigned short u; } cv;
    cv.h = __float2bfloat16(x);  // RNE
    return cv.u;
}

// ---------------- pass 1: fp32 -> bf16 convert ----------------
__global__ __launch_bounds__(256) void convert_f32_bf16(
    const float* __restrict__ in, unsigned short* __restrict__ out) {
    const int idx = (blockIdx.x * 256 + threadIdx.x) * 8;
    float4 v0 = *(const float4*)(in + idx);
    float4 v1 = *(const float4*)(in + idx + 4);
    ushort8v o;
    o[0] = f2bf(v0.x); o[1] = f2bf(v0.y); o[2] = f2bf(v0.z); o[3] = f2bf(v0.w);
    o[4] = f2bf(v1.x); o[5] = f2bf(v1.y); o[6] = f2bf(v1.z); o[7] = f2bf(v1.w);
    *(ushort8v*)(out + idx) = o;  // 16B store
}

// ---------------- pass 2: bf16 MFMA GEMM (32x32x16) ----------------
// LDS: tile as 128 rows x 8 chunks (chunk = 8 bf16 = 16B); chunk c of row r at
// slot r*8 + (c ^ (r&7)).  global_load_lds fills slots in lane order; each lane
// fetches the global chunk belonging in its slot.
__global__ __launch_bounds__(256) void gemm_bf16(
    const unsigned short* __restrict__ A,   // [M,K] bf16
    const unsigned short* __restrict__ W,   // [N,K] bf16
    const float* __restrict__ bias,         // [N]
    float* __restrict__ C)                  // [M,N] fp32
{
    __shared__ unsigned short As[BM * BK];  // 16 KB
    __shared__ unsigned short Bs[BN * BK];  // 16 KB

    const int tid  = threadIdx.x;
    const int wave = tid >> 6;
    const int lane = tid & 63;
    // grid swizzle: n varies fastest -> 8 blocks of one M-tile are adjacent
    const int bid  = blockIdx.x;
    const int bm0  = (bid >> 3) * BM;
    const int bn0  = (bid & 7) * BN;
    const int wr   = wave >> 1;        // wave row slab (64)
    const int wc   = wave & 1;         // wave col slab (64)
    const int l31  = lane & 31;
    const int half = lane >> 5;        // 0..1

    f32x16 acc[2][2];
#pragma unroll
    for (int i = 0; i < 2; ++i)
#pragma unroll
        for (int j = 0; j < 2; ++j)
#pragma unroll
            for (int r = 0; r < 16; ++r)
                acc[i][j][r] = 0.f;

    const unsigned short* Ag = A + (size_t)bm0 * K_DIM;
    const unsigned short* Wg = W + (size_t)bn0 * K_DIM;

    for (int kt = 0; kt < K_DIM; kt += BK) {
        __syncthreads();
#pragma unroll
        for (int p = 0; p < 4; ++p) {
            const int s     = p * 256 + wave * 64 + lane;
            const int row   = s >> 3;
            const int c     = (s & 7) ^ (row & 7);
            const int goff  = row * K_DIM + kt + c * 8;    // elems
            const int lbase = (p * 256 + wave * 64) * 8;   // elems (wave-uniform)
            __builtin_amdgcn_global_load_lds((gptr_t)(Ag + goff), (lptr_t)(As + lbase), 16, 0, 0);
            __builtin_amdgcn_global_load_lds((gptr_t)(Wg + goff), (lptr_t)(Bs + lbase), 16, 0, 0);
        }
        __syncthreads();

#pragma unroll
        for (int ks = 0; ks < 4; ++ks) {           // 4 k-steps of K=16
            const int kc = ks * 2 + half;          // chunk index (8 elems)
            bf16x8 af[2], bf[2];
#pragma unroll
            for (int i = 0; i < 2; ++i) {
                const int arow = wr * 64 + i * 32 + l31;
                af[i] = *(const bf16x8*)(As + arow * 64 + (kc ^ (arow & 7)) * 8);
                const int brow = wc * 64 + i * 32 + l31;
                bf[i] = *(const bf16x8*)(Bs + brow * 64 + (kc ^ (brow & 7)) * 8);
            }
#pragma unroll
            for (int i = 0; i < 2; ++i)
#pragma unroll
                for (int j = 0; j < 2; ++j)
                    acc[i][j] = __builtin_amdgcn_mfma_f32_32x32x16_bf16(
                        af[i], bf[j], acc[i][j], 0, 0, 0);
        }
    }

    // epilogue: +bias, fp32 store.
    // C/D 32x32: col = lane&31, row = (reg&3) + 8*(reg>>2) + 4*(lane>>5)  [m74/m101]
#pragma unroll
    for (int j = 0; j < 2; ++j) {
        const int col = bn0 + wc * 64 + j * 32 + l31;
        const float bj = bias[col];
#pragma unroll
        for (int i = 0; i < 2; ++i) {
            const int rbase = bm0 + wr * 64 + i * 32 + 4 * half;
#pragma unroll
            for (int reg = 0; reg < 16; ++reg) {
                const int row = rbase + (reg & 3) + 8 * (reg >> 2);
                C[(size_t)row * N_DIM + col] = acc[i][j][reg] + bj;
            }
        }
    }
}

// ---------------- fallback (fused) if d_ws too small ----------------
#define LDK 40
__global__ __launch_bounds__(256) void groupfc_fused(
    const float* __restrict__ A, const float* __restrict__ W,
    const float* __restrict__ bias, float* __restrict__ C)
{
    __shared__ unsigned short As[BM * LDK];
    __shared__ unsigned short Bs[BN * LDK];
    const int tid = threadIdx.x;
    const int bm0 = blockIdx.x * BM, bn0 = blockIdx.y * BN;
    const int wave = tid >> 6, lane = tid & 63;
    const int wr = wave >> 1, wc = wave & 1;
    const int l15 = lane & 15, quad = lane >> 4;
    f32x4 acc[4][4];
#pragma unroll
    for (int i = 0; i < 4; ++i)
#pragma unroll
        for (int j = 0; j < 4; ++j) acc[i][j] = (f32x4){0.f, 0.f, 0.f, 0.f};
    const int srow = tid >> 3, sf4 = tid & 7;
    const float* Ag = A + bm0 * K_DIM;
    const float* Wg = W + bn0 * K_DIM;
    for (int kt = 0; kt < K_DIM; kt += 32) {
        __syncthreads();
        float4 av[4], bv[4];
#pragma unroll
        for (int p = 0; p < 4; ++p) {
            const int row = p * 32 + srow;
            av[p] = *(const float4*)(Ag + row * K_DIM + kt + sf4 * 4);
            bv[p] = *(const float4*)(Wg + row * K_DIM + kt + sf4 * 4);
        }
#pragma unroll
        for (int p = 0; p < 4; ++p) {
            const int row = p * 32 + srow;
            ushort4 a16, b16;
            a16.x = f2bf(av[p].x); a16.y = f2bf(av[p].y);
            a16.z = f2bf(av[p].z); a16.w = f2bf(av[p].w);
            b16.x = f2bf(bv[p].x); b16.y = f2bf(bv[p].y);
            b16.z = f2bf(bv[p].z); b16.w = f2bf(bv[p].w);
            *(ushort4*)(&As[row * LDK + sf4 * 4]) = a16;
            *(ushort4*)(&Bs[row * LDK + sf4 * 4]) = b16;
        }
        __syncthreads();
        bf16x8 af[4], bfv[4];
#pragma unroll
        for (int i = 0; i < 4; ++i) {
            af[i]  = *(const bf16x8*)(&As[(wr * 64 + i * 16 + l15) * LDK + quad * 8]);
            bfv[i] = *(const bf16x8*)(&Bs[(wc * 64 + i * 16 + l15) * LDK + quad * 8]);
        }
#pragma unroll
        for (int i = 0; i < 4; ++i)
#pragma unroll
            for (int j = 0; j < 4; ++j)
                acc[i][j] = __builtin_amdgcn_mfma_f32_16x16x32_bf16(af[i], bfv[j], acc[i][j], 0, 0, 0);
    }
#pragma unroll
    for (int j = 0; j < 4; ++j) {
        const int col = bn0 + wc * 64 + j * 16 + l15;
        const float bj = bias[col];
#pragma unroll
        for (int i = 0; i < 4; ++i) {
            const int row0 = bm0 + wr * 64 + i * 16 + quad * 4;
#pragma unroll
            for (int r = 0; r < 4; ++r) C[(row0 + r) * N_DIM + col] = acc[i][j][r] + bj;
        }
    }
}

extern "C" void kernel_launch(void* const* d_in, const int* in_sizes, int n_in,
                              void* d_out, int out_size, void* d_ws, size_t ws_size,
                              hipStream_t stream) {
    const float* A    = (const float*)d_in[0];
    const float* W    = (const float*)d_in[1];
    const float* bias = (const float*)d_in[2];
    float* C          = (float*)d_out;

    const size_t a_elems = (size_t)M_DIM * K_DIM;
    const size_t w_elems = (size_t)N_DIM * K_DIM;
    const size_t need    = (a_elems + w_elems) * sizeof(unsigned short);  // ~66 MB

    if (ws_size >= need) {
        unsigned short* Abf = (unsigned short*)d_ws;
        unsigned short* Wbf = Abf + a_elems;
        convert_f32_bf16<<<dim3(a_elems / (256 * 8)), dim3(256), 0, stream>>>(A, Abf);
        convert_f32_bf16<<<dim3(w_elems / (256 * 8)), dim3(256), 0, stream>>>(W, Wbf);
        gemm_bf16<<<dim3((M_DIM / BM) * (N_DIM / BN)), dim3(256), 0, stream>>>(Abf, Wbf, bias, C);
    } else {
        dim3 grid(M_DIM / BM, N_DIM / BN);
        groupfc_fused<<<grid, dim3(256), 0, stream>>>(A, W, bias, C);
    }
}